// Round 19
// baseline (142.188 us; speedup 1.0000x reference)
//
#include <hip/hip_runtime.h>
#include <hip/hip_bf16.h>

// MultiheadAttention: B=8, T=S=1024, n_heads=8, d_head=128, D=1024.
// Pipeline (7 kernels): detect dtype -> cvt (x + weights merged) -> QKV proj
// GEMM (64x128 block tile, 2x2 waves of 32x64, low-VGPR) -> split-S flash
// attention (QBLK=16, 8-wave blocks, LDS K/V staging, dbuf, swizzles,
// defer-max, XCD swizzle) -> combine -> out-proj split-K (reg ping-pong)
// -> reduce+bias.

typedef __attribute__((ext_vector_type(8))) short short8;
typedef __attribute__((ext_vector_type(4))) short short4v;
typedef __attribute__((ext_vector_type(4))) float f32x4;

#define B_   8
#define S_   1024
#define DH_  128
#define NH_  8
#define DM_  1024

#define MFMA16(a, b, c) __builtin_amdgcn_mfma_f32_16x16x32_bf16((a), (b), (c), 0, 0, 0)

#define GLOAD_LDS16(gsrc, ldst)                                              \
  __builtin_amdgcn_global_load_lds(                                          \
      (const __attribute__((address_space(1))) void*)(gsrc),                 \
      (__attribute__((address_space(3))) void*)(ldst), 16, 0, 0)

__device__ __forceinline__ float bf2f(unsigned short u) {
  union { unsigned int i; float f; } x; x.i = ((unsigned int)u) << 16; return x.f;
}
__device__ __forceinline__ unsigned short f2bf(float f) {
  union { float f; unsigned int i; } x; x.f = f;
  unsigned int r = (x.i + 0x7fffu + ((x.i >> 16) & 1u)) >> 16;
  return (unsigned short)r;
}
__device__ __forceinline__ unsigned short f2h(float f) {
  union { _Float16 h; unsigned short u; } x; x.h = (_Float16)f; return x.u;
}
__device__ __forceinline__ float h2f(unsigned short u) {
  union { unsigned short u; _Float16 h; } x; x.u = u; return (float)x.h;
}
__device__ __forceinline__ float ldany(const void* p, int i, int fp) {
  return fp ? ((const float*)p)[i] : bf2f(((const unsigned short*)p)[i]);
}

// ---------------- D: input dtype detection ----------------
__global__ void k_detect(const unsigned short* __restrict__ in, int* __restrict__ flag) {
  __shared__ int f;
  int tid = threadIdx.x;
  if (tid == 0) f = 0;
  __syncthreads();
  int t = 0;
  for (int i = tid; i < 16384; i += 256) {
    unsigned h = in[i];
    unsigned e = (h >> 7) & 0xFFu, m = h & 0x7Fu;
    if (e == 0xFFu || (e == 0u && m != 0u)) t = 1;
  }
  if (t) atomicOr(&f, 1);
  __syncthreads();
  if (tid == 0) *flag = f;  // 1 = fp32, 0 = bf16
}

// ---------------- C: merged conversion (q/k/v x8-vec + weights/biases) ----------------
__global__ void k_cvt(const void* __restrict__ q, const void* __restrict__ k,
                      const void* __restrict__ v,
                      const void* __restrict__ Wq, const void* __restrict__ Wk,
                      const void* __restrict__ Wv, const void* __restrict__ Wo,
                      const void* __restrict__ bq, const void* __restrict__ bk,
                      const void* __restrict__ bv, const void* __restrict__ bo,
                      const int* __restrict__ flag,
                      unsigned short* __restrict__ Xq, unsigned short* __restrict__ Xk,
                      unsigned short* __restrict__ Xv,
                      unsigned short* __restrict__ wqT, unsigned short* __restrict__ wkT,
                      unsigned short* __restrict__ wvT, unsigned short* __restrict__ woT,
                      unsigned short* __restrict__ bqc, unsigned short* __restrict__ bkc,
                      unsigned short* __restrict__ bvc, unsigned short* __restrict__ boc) {
  const int fp = *flag;
  if (blockIdx.x < 1536) {
    int z = blockIdx.x / 512, blk = blockIdx.x % 512;
    const void* in = (z == 0) ? q : (z == 1) ? k : v;
    unsigned short* out = (z == 0) ? Xq : (z == 1) ? Xk : Xv;
    int e8 = (blk * 256 + threadIdx.x) * 8;
    if (fp) {
      const float* xf = (const float*)in + e8;
      f32x4 x0 = *(const f32x4*)xf;
      f32x4 x1 = *(const f32x4*)(xf + 4);
      short8 o;
#pragma unroll
      for (int j = 0; j < 4; ++j) { o[j] = (short)f2bf(x0[j]); o[4 + j] = (short)f2bf(x1[j]); }
      *(short8*)&out[e8] = o;
    } else {
      *(short8*)&out[e8] = *(const short8*)((const unsigned short*)in + e8);
    }
    return;
  }
  int g = (blockIdx.x - 1536) * 256 + threadIdx.x;
  if (g < 393216) {
    int z = g >> 17, e = g & 131071;
    const void* in = (z == 0) ? Wq : (z == 1) ? Wk : Wv;
    unsigned short* out = (z == 0) ? wqT : (z == 1) ? wkT : wvT;
    int r = e >> 10, c = e & 1023;
    out[c * 128 + r] = f2bf(ldany(in, e, fp));
  } else if (g < 524288) {
    int e = g - 393216;
    int r = e >> 7, c = e & 127;
    woT[c * 1024 + r] = f2bf(ldany(Wo, e, fp));
  } else if (g < 525312) {
    int e = g - 524288; bqc[e] = f2bf(ldany(bq, e, fp));
  } else if (g < 526336) {
    int e = g - 525312; bkc[e] = f2bf(ldany(bk, e, fp));
  } else if (g < 527360) {
    int e = g - 526336; bvc[e] = f2bf(ldany(bv, e, fp));
  } else if (g < 527488) {
    int e = g - 527360; boc[e] = f2bf(ldany(bo, e, fp));
  }
}

// ---------------- K1: fused QKV projection GEMM ----------------
// grid (128, 8, 3), block 256 (4 waves, 2x2 over 64m x 128n; wave tile 32x64).
// Per wave: a[2][4] + acc[2][4] + bfr[2][4] ~116 VGPR -> 4 waves/SIMD tier.
// Duplication ratios identical to the 128x128 variant (A x2 by wn, B x2 by wm).
__global__ __launch_bounds__(256) void k_qkv(
    const unsigned short* __restrict__ Xq, const unsigned short* __restrict__ Xk,
    const unsigned short* __restrict__ Xv,
    const unsigned short* __restrict__ WqT, const unsigned short* __restrict__ WkT,
    const unsigned short* __restrict__ WvT,
    const unsigned short* __restrict__ bq, const unsigned short* __restrict__ bk,
    const unsigned short* __restrict__ bv,
    unsigned short* __restrict__ Qp, unsigned short* __restrict__ Kp,
    unsigned short* __restrict__ VpT) {
  __shared__ __align__(16) unsigned short vtile[64][136];

  const int mat = blockIdx.z;
  const unsigned short* X    = (mat == 0) ? Xq  : (mat == 1) ? Xk  : Xv;
  const unsigned short* WT   = (mat == 0) ? WqT : (mat == 1) ? WkT : WvT;
  const unsigned short* bias = (mat == 0) ? bq  : (mat == 1) ? bk  : bv;
  const float scale = (mat == 0) ? (1.4426950408889634f / 11.313708498984761f) : 1.0f;

  const int tid = threadIdx.x, lane = tid & 63, wave = tid >> 6;
  const int wm = wave >> 1, wn = wave & 1;
  const int l15 = lane & 15, lg = lane >> 4;
  const int mbase = blockIdx.x * 64 + wm * 32;
  const int nbase = blockIdx.y * 128 + wn * 64;

  short8 a[2][4];
#pragma unroll
  for (int mi = 0; mi < 2; ++mi)
#pragma unroll
    for (int kk = 0; kk < 4; ++kk)
      a[mi][kk] = *(const short8*)&X[(mbase + mi * 16 + l15) * DH_ + kk * 32 + lg * 8];

  f32x4 acc[2][4];
#pragma unroll
  for (int mi = 0; mi < 2; ++mi)
#pragma unroll
    for (int ni = 0; ni < 4; ++ni) acc[mi][ni] = (f32x4){0.f, 0.f, 0.f, 0.f};

  short8 bfr[2][4];
#pragma unroll
  for (int kk = 0; kk < 4; ++kk)
    bfr[0][kk] = *(const short8*)&WT[(nbase + l15) * DH_ + kk * 32 + lg * 8];

#pragma unroll
  for (int ni = 0; ni < 4; ++ni) {
    if (ni < 3) {
#pragma unroll
      for (int kk = 0; kk < 4; ++kk)
        bfr[(ni + 1) & 1][kk] =
            *(const short8*)&WT[(nbase + (ni + 1) * 16 + l15) * DH_ + kk * 32 + lg * 8];
    }
#pragma unroll
    for (int mi = 0; mi < 2; ++mi)
#pragma unroll
      for (int kk = 0; kk < 4; ++kk)
        acc[mi][ni] = MFMA16(a[mi][kk], bfr[ni & 1][kk], acc[mi][ni]);
  }

  // stage C tile (bias + scale applied) into vtile
#pragma unroll
  for (int mi = 0; mi < 2; ++mi)
#pragma unroll
    for (int ni = 0; ni < 4; ++ni) {
      int nl = wn * 64 + ni * 16 + l15;
      float bv_ = bf2f(bias[blockIdx.y * 128 + nl]);
#pragma unroll
      for (int reg = 0; reg < 4; ++reg) {
        int ml_ = wm * 32 + mi * 16 + lg * 4 + reg;
        vtile[ml_][nl] = f2bf((acc[mi][ni][reg] + bv_) * scale);
      }
    }
  __syncthreads();

  const int b = blockIdx.x >> 4;   // 16 blocks of 64 rows per batch
  const int h = blockIdx.y;
  if (mat < 2) {
    // contiguous 16KB region: rows t0..t0+64 of head h, full d
    unsigned short* Out = ((mat == 0) ? Qp : Kp) +
        ((b * NH_ + h) * S_ + (blockIdx.x & 15) * 64) * DH_;
#pragma unroll
    for (int j = 0; j < 4; ++j) {
      int r = j * 16 + (tid >> 4);
      int c0 = (tid & 15) * 8;
      short8 v = *(const short8*)&vtile[r][c0];
      *(short8*)&Out[j * 2048 + tid * 8] = v;
    }
  } else {
    int n = tid >> 1;               // dh 0..127
    int thalf = (tid & 1) * 32;     // t-half within the 64-row m tile
    int base = ((b * NH_ + h) * DH_ + n) * S_ + (blockIdx.x & 15) * 64 + thalf;
#pragma unroll
    for (int jj = 0; jj < 4; ++jj) {
      short8 v;
#pragma unroll
      for (int j2 = 0; j2 < 8; ++j2) v[j2] = (short)vtile[thalf + jj * 8 + j2][n];
      *(short8*)&VpT[base + jj * 8] = v;
    }
  }
}

// ---------------- K2: split-S flash attention, 8-wave blocks, QBLK=16 ----------------
// 1280 blocks x 8 waves (512 thr). Block = (bh, G 0..7 of 8 q-waves, chunk c).
// K/V tiles staged ONCE per block (2 gload/wave), dbuf; K slot-swizzle,
// V granule-swizzle. LDS 44032 -> 3 blocks/CU x 8 waves = 24 waves/CU.
__global__ __launch_bounds__(512) void k_attn_split(
    const unsigned short* __restrict__ Qp, const unsigned short* __restrict__ Kp,
    const unsigned short* __restrict__ VpT,
    unsigned short* __restrict__ Opart, float* __restrict__ ml,
    unsigned short* __restrict__ O) {
  __shared__ __align__(16) unsigned short kbuf[2][4096];  // [32 s][128 d], slot-swizzled
  __shared__ __align__(16) unsigned short vbuf[2][4096];  // [128 d][32 t], granule-swizzled
  __shared__ __align__(16) unsigned short plds[8][16][44];

  const int tid = threadIdx.x, lane = tid & 63, w = tid >> 6;  // w 0..7
  const int l15 = lane & 15, lg = lane >> 4;

  const int bid = blockIdx.x;                      // 1280 = 8 XCD x 160
  const int swz = (bid & 7) * 160 + (bid >> 3);
  const int bh = swz / 20;
  const int bj = swz % 20;                         // heavy (8-tile) blocks first
  int G, c;
  if (bj < 4)        { G = 7; c = bj; }
  else if (bj < 7)   { G = 6; c = bj - 4; }
  else if (bj < 10)  { G = 5; c = bj - 7; }
  else if (bj < 12)  { G = 4; c = bj - 10; }
  else if (bj < 14)  { G = 3; c = bj - 12; }
  else if (bj == 14) { G = 2; c = 0; }
  else if (bj == 15) { G = 1; c = 0; }
  else if (bj == 16) { G = 6; c = 3; }
  else if (bj == 17) { G = 4; c = 2; }
  else if (bj == 18) { G = 2; c = 1; }
  else               { G = 0; c = 0; }
  const int qw = 8 * G + w;                        // 0..63, QBLK=16
  const int q0 = qw * 16;
  const int cd = G >> 1;                           // diagonal chunk (shared by 8 waves)
  const bool dia = (c == cd);
  const int sbeg = c * 256;
  const int nt_w   = dia ? ((qw >> 1) + 1 - 8 * c) : 8;
  const int nt_blk = dia ? (4 * G + 4 - 8 * c) : 8;

  const unsigned short* Qb = Qp + bh * (S_ * DH_);
  const unsigned short* Kb = Kp + bh * (S_ * DH_);
  const unsigned short* Vb = VpT + bh * (DH_ * S_);

  // staging roles: wave w stages K rows [w*4,w*4+4) and V d-rows [w*16,w*16+16)
  const int krow = w * 4 + (lane >> 4);
  const int kslot = lane & 15;
  const int vd   = w * 16 + (lane >> 2);
  const int vslot = lane & 3;
  const int vsw  = vslot ^ ((vd >> 1) & 3);       // inverse-swizzled V source granule

#define STAGE(bb, sb_) do {                                                        \
    GLOAD_LDS16(Kb + ((sb_) + krow) * DH_ + ((kslot ^ (krow & 7)) * 8),            \
                &kbuf[bb][(w * 4) * 128]);                                         \
    GLOAD_LDS16(Vb + vd * S_ + (sb_) + vsw * 8, &vbuf[bb][(w * 16) * 32]);         \
  } while (0)

  short8 qf[4];
#pragma unroll
  for (int kk = 0; kk < 4; ++kk)
    qf[kk] = *(const short8*)&Qb[(q0 + l15) * DH_ + kk * 32 + lg * 8];

  short8 ones;
#pragma unroll
  for (int jj = 0; jj < 8; ++jj) ones[jj] = (short)0x3F80;  // bf16 1.0

  f32x4 of[8], l_acc;
  float m_[4];
#pragma unroll
  for (int di = 0; di < 8; ++di) of[di] = (f32x4){0.f, 0.f, 0.f, 0.f};
  l_acc = (f32x4){0.f, 0.f, 0.f, 0.f};
#pragma unroll
  for (int reg = 0; reg < 4; ++reg) m_[reg] = -1e30f;

  STAGE(0, sbeg);
  __syncthreads();

  const int vrd = lg ^ ((l15 >> 1) & 3);  // swizzled V read granule
  for (int kt = 0; kt < nt_blk; ++kt) {
    const int cb = kt & 1;
    if (kt + 1 < nt_blk) STAGE(cb ^ 1, sbeg + (kt + 1) * 32);  // prefetch under compute

    if (kt < nt_w) {
      const int sb = sbeg + kt * 32;
      const int xsl = l15 & 7;

      f32x4 s0 = (f32x4){0.f, 0.f, 0.f, 0.f}, s1 = (f32x4){0.f, 0.f, 0.f, 0.f};
#pragma unroll
      for (int kk = 0; kk < 4; ++kk) {
        short8 kf0 = *(const short8*)&kbuf[cb][l15 * 128 + (((kk * 4 + lg) ^ xsl) * 8)];
        short8 kf1 = *(const short8*)&kbuf[cb][(16 + l15) * 128 + (((kk * 4 + lg) ^ xsl) * 8)];
        s0 = MFMA16(qf[kk], kf0, s0);
        s1 = MFMA16(qf[kk], kf1, s1);
      }

      if (dia && kt == nt_w - 1) {
        const int qrow = q0 + lg * 4;
#pragma unroll
        for (int reg = 0; reg < 4; ++reg) {
          if (sb + l15 > qrow + reg)      s0[reg] = -1e30f;
          if (sb + 16 + l15 > qrow + reg) s1[reg] = -1e30f;
        }
      }

      // defer-max: rescale only when a row's max grew past m_ + 8
      bool need = false;
      float vmax[4];
#pragma unroll
      for (int reg = 0; reg < 4; ++reg) {
        vmax[reg] = fmaxf(s0[reg], s1[reg]);
        need |= (vmax[reg] > m_[reg] + 8.0f);
      }
      if (__any(need)) {
        float alpha[4];
#pragma unroll
        for (int reg = 0; reg < 4; ++reg) {
          float rm = vmax[reg];
#pragma unroll
          for (int d = 1; d < 16; d <<= 1) rm = fmaxf(rm, __shfl_xor(rm, d));
          float mn = fmaxf(m_[reg], rm);
          alpha[reg] = __builtin_amdgcn_exp2f(m_[reg] - mn);
          m_[reg] = mn;
        }
#pragma unroll
        for (int di = 0; di < 8; ++di)
#pragma unroll
          for (int reg = 0; reg < 4; ++reg) of[di][reg] *= alpha[reg];
#pragma unroll
        for (int reg = 0; reg < 4; ++reg) l_acc[reg] *= alpha[reg];
      }

#pragma unroll
      for (int reg = 0; reg < 4; ++reg) {
        float p0 = __builtin_amdgcn_exp2f(s0[reg] - m_[reg]);
        float p1 = __builtin_amdgcn_exp2f(s1[reg] - m_[reg]);
        union { float f; unsigned int i; } u0, u1;
        u0.f = p0; u1.f = p1;
        plds[w][lg * 4 + reg][l15]      = (unsigned short)((u0.i + 0x8000u) >> 16);
        plds[w][lg * 4 + reg][16 + l15] = (unsigned short)((u1.i + 0x8000u) >> 16);
      }

      short8 pa = *(const short8*)&plds[w][l15][lg * 8];

#pragma unroll
      for (int di = 0; di < 8; ++di) {
        short8 vfd = *(const short8*)&vbuf[cb][(di * 16 + l15) * 32 + vrd * 8];
        of[di] = MFMA16(pa, vfd, of[di]);
      }
      l_acc = MFMA16(pa, ones, l_acc);
    }
    __syncthreads();
  }

  if (qw < 16) {
    // single-chunk causal row: write O directly
    const int b = bh >> 3, h = bh & 7;
#pragma unroll
    for (int reg = 0; reg < 4; ++reg) {
      int row = lg * 4 + reg;
      float inv = 1.0f / l_acc[reg];
      int qq = q0 + row;
#pragma unroll
      for (int di = 0; di < 8; ++di)
        O[(b * S_ + qq) * DM_ + h * DH_ + di * 16 + l15] = f2bf(of[di][reg] * inv);
    }
  } else {
    int runit;
    if (qw < 32)      runit = 16 + 2 * (qw - 16) + c;
    else if (qw < 48) runit = 48 + 3 * (qw - 32) + c;
    else              runit = 96 + 4 * (qw - 48) + c;
    const int g = bh * 160 + runit;
    unsigned short* op = Opart + g * 2048;
    float* mlg = ml + g * 32;
#pragma unroll
    for (int reg = 0; reg < 4; ++reg) {
      int row = lg * 4 + reg;
      float inv = 1.0f / l_acc[reg];
#pragma unroll
      for (int di = 0; di < 8; ++di)
        op[row * 128 + di * 16 + l15] = f2h(of[di][reg] * inv);
      if (l15 == 0) {
        mlg[row * 2]     = m_[reg];
        mlg[row * 2 + 1] = l_acc[reg];
      }
    }
  }
#undef STAGE
}

// ---------------- K2b: combine partials (qw >= 16 only) -> O bf16 ----------------
__global__ void k_combine(const unsigned short* __restrict__ Opart,
                          const float* __restrict__ ml,
                          unsigned short* __restrict__ O) {
  const int bh = blockIdx.x / 48, qw = 16 + blockIdx.x % 48;
  const int nc = (qw >> 4) + 1;  // 2..4
  const int rbase = (qw < 32) ? 16 + 2 * (qw - 16)
                  : (qw < 48) ? 48 + 3 * (qw - 32)
                              : 96 + 4 * (qw - 48);
  const int g0 = bh * 160 + rbase;
  const int tid = threadIdx.x;
  const int row = tid >> 4, d0 = (tid & 15) * 8;

  float m[4], l[4];
  float mx = -1e30f;
  for (int i = 0; i < nc; ++i) {
    m[i] = ml[(g0 + i) * 32 + row * 2];
    l[i] = ml[(g0 + i) * 32 + row * 2 + 1];
    mx = fmaxf(mx, m[i]);
  }
  float wt[4], wsum = 0.f;
  for (int i = 0; i < nc; ++i) { wt[i] = l[i] * exp2f(m[i] - mx); wsum += wt[i]; }
  float invw = 1.0f / wsum;

  float acc[8];
#pragma unroll
  for (int jj = 0; jj < 8; ++jj) acc[jj] = 0.f;
  for (int i = 0; i < nc; ++i) {
    short8 v = *(const short8*)&Opart[(g0 + i) * 2048 + row * 128 + d0];
    float wgt = wt[i];
#pragma unroll
    for (int jj = 0; jj < 8; ++jj) acc[jj] += wgt * h2f((unsigned short)v[jj]);
  }

  const int b = bh >> 3, h = bh & 7;
  const int qq = qw * 16 + row;
  short8 o;
#pragma unroll
  for (int jj = 0; jj < 8; ++jj) o[jj] = (short)f2bf(acc[jj] * invw);
  *(short8*)&O[(b * S_ + qq) * DM_ + h * DH_ + d0] = o;
}

// ---------------- K2-fallback: single-pass causal flash attention ----------------
__global__ __launch_bounds__(256) void k_attn(
    const unsigned short* __restrict__ Qp, const unsigned short* __restrict__ Kp,
    const unsigned short* __restrict__ VpT, unsigned short* __restrict__ O) {
  __shared__ __align__(16) unsigned short plds[4][2][16][44];

  const int qt = 7 - blockIdx.x;
  const int bh = blockIdx.y;
  const int tid = threadIdx.x, lane = tid & 63, w = tid >> 6;
  const int l15 = lane & 15, lg = lane >> 4;
  const int q0 = qt * 128 + w * 32;

  const unsigned short* Qb = Qp + bh * (S_ * DH_);
  const unsigned short* Kb = Kp + bh * (S_ * DH_);
  const unsigned short* Vb = VpT + bh * (DH_ * S_);

  short8 qf[2][4];
#pragma unroll
  for (int mi = 0; mi < 2; ++mi)
#pragma unroll
    for (int kk = 0; kk < 4; ++kk)
      qf[mi][kk] = *(const short8*)&Qb[(q0 + mi * 16 + l15) * DH_ + kk * 32 + lg * 8];

  f32x4 of[2][8];
  float m_[2][4], l_[2][4];
#pragma unroll
  for (int mi = 0; mi < 2; ++mi) {
#pragma unroll
    for (int di = 0; di < 8; ++di) of[mi][di] = (f32x4){0.f, 0.f, 0.f, 0.f};
#pragma unroll
    for (int reg = 0; reg < 4; ++reg) { m_[mi][reg] = -1e30f; l_[mi][reg] = 0.f; }
  }

  const int ntiles = q0 / 32 + 1;
  for (int kt = 0; kt < ntiles; ++kt) {
    const int sb = kt * 32;
    const bool lastt = (kt == ntiles - 1);

    f32x4 s[2][2];
#pragma unroll
    for (int mi = 0; mi < 2; ++mi)
#pragma unroll
      for (int ni = 0; ni < 2; ++ni) s[mi][ni] = (f32x4){0.f, 0.f, 0.f, 0.f};
#pragma unroll
    for (int ni = 0; ni < 2; ++ni) {
      short8 kf[4];
#pragma unroll
      for (int kk = 0; kk < 4; ++kk)
        kf[kk] = *(const short8*)&Kb[(sb + ni * 16 + l15) * DH_ + kk * 32 + lg * 8];
#pragma unroll
      for (int mi = 0; mi < 2; ++mi)
#pragma unroll
        for (int kk = 0; kk < 4; ++kk)
          s[mi][ni] = MFMA16(qf[mi][kk], kf[kk], s[mi][ni]);
    }

#pragma unroll
    for (int mi = 0; mi < 2; ++mi) {
      float alpha[4];
#pragma unroll
      for (int reg = 0; reg < 4; ++reg) {
        int q = q0 + mi * 16 + lg * 4 + reg;
        float v0 = s[mi][0][reg];
        float v1 = s[mi][1][reg];
        if (lastt) {
          if (sb + l15 > q)      v0 = -1e30f;
          if (sb + 16 + l15 > q) v1 = -1e30f;
        }
        float rmax = fmaxf(v0, v1);
#pragma unroll
        for (int d = 1; d < 16; d <<= 1) rmax = fmaxf(rmax, __shfl_xor(rmax, d));
        float mn = fmaxf(m_[mi][reg], rmax);
        alpha[reg] = __builtin_amdgcn_exp2f(m_[mi][reg] - mn);
        m_[mi][reg] = mn;
        float p0 = __builtin_amdgcn_exp2f(v0 - mn), p1 = __builtin_amdgcn_exp2f(v1 - mn);
        float rs = p0 + p1;
#pragma unroll
        for (int d = 1; d < 16; d <<= 1) rs += __shfl_xor(rs, d);
        l_[mi][reg] = l_[mi][reg] * alpha[reg] + rs;
        plds[w][mi][lg * 4 + reg][l15]      = f2bf(p0);
        plds[w][mi][lg * 4 + reg][16 + l15] = f2bf(p1);
      }
#pragma unroll
      for (int di = 0; di < 8; ++di)
#pragma unroll
        for (int reg = 0; reg < 4; ++reg) of[mi][di][reg] *= alpha[reg];
    }

    short8 pa[2];
#pragma unroll
    for (int mi = 0; mi < 2; ++mi)
      pa[mi] = *(const short8*)&plds[w][mi][l15][lg * 8];

#pragma unroll
    for (int di = 0; di < 8; ++di) {
      short8 vf = *(const short8*)&Vb[(di * 16 + l15) * S_ + sb + lg * 8];
#pragma unroll
      for (int mi = 0; mi < 2; ++mi) of[mi][di] = MFMA16(pa[mi], vf, of[mi][di]);
    }
  }

  const int b = bh >> 3, h = bh & 7;
#pragma unroll
  for (int mi = 0; mi < 2; ++mi)
#pragma unroll
    for (int reg = 0; reg < 4; ++reg) {
      float inv = 1.0f / l_[mi][reg];
      int q = q0 + mi * 16 + lg * 4 + reg;
#pragma unroll
      for (int di = 0; di < 8; ++di) {
        int d = di * 16 + l15;
        O[(b * S_ + q) * DM_ + h * DH_ + d] = f2bf(of[mi][di][reg] * inv);
      }
    }
}

// ---------------- K3: out-proj split-K GEMM (reg ping-pong) ----------------
__global__ __launch_bounds__(256) void k_oproj(
    const unsigned short* __restrict__ O, const unsigned short* __restrict__ WoT,
    float* __restrict__ outacc) {
  const int tid = threadIdx.x, lane = tid & 63, wave = tid >> 6;
  const int wm = wave >> 1, wn = wave & 1;
  const int l15 = lane & 15, lg = lane >> 4;
  const int mbase = blockIdx.x * 128 + wm * 64;
  const int kc = blockIdx.y;

  f32x4 acc[4][4];
#pragma unroll
  for (int mi = 0; mi < 4; ++mi)
#pragma unroll
    for (int ni = 0; ni < 4; ++ni) acc[mi][ni] = (f32x4){0.f, 0.f, 0.f, 0.f};

  short8 a[2][4], bfr[2][4];
  {
    int kb = kc * 256;
#pragma unroll
    for (int mi = 0; mi < 4; ++mi)
      a[0][mi] = *(const short8*)&O[(mbase + mi * 16 + l15) * DM_ + kb + lg * 8];
#pragma unroll
    for (int ni = 0; ni < 4; ++ni)
      bfr[0][ni] = *(const short8*)&WoT[(wn * 64 + ni * 16 + l15) * DM_ + kb + lg * 8];
  }

#pragma unroll
  for (int ks = 0; ks < 8; ++ks) {
    const int cur = ks & 1;
    if (ks < 7) {
      int kb = kc * 256 + (ks + 1) * 32;
#pragma unroll
      for (int mi = 0; mi < 4; ++mi)
        a[cur ^ 1][mi] = *(const short8*)&O[(mbase + mi * 16 + l15) * DM_ + kb + lg * 8];
#pragma unroll
      for (int ni = 0; ni < 4; ++ni)
        bfr[cur ^ 1][ni] = *(const short8*)&WoT[(wn * 64 + ni * 16 + l15) * DM_ + kb + lg * 8];
    }
#pragma unroll
    for (int mi = 0; mi < 4; ++mi)
#pragma unroll
      for (int ni = 0; ni < 4; ++ni)
        acc[mi][ni] = MFMA16(a[cur][mi], bfr[cur][ni], acc[mi][ni]);
  }

  float* oa = outacc + kc * (8192 * 128);
#pragma unroll
  for (int mi = 0; mi < 4; ++mi)
#pragma unroll
    for (int ni = 0; ni < 4; ++ni) {
      int n = wn * 64 + ni * 16 + l15;
#pragma unroll
      for (int reg = 0; reg < 4; ++reg) {
        int m = mbase + mi * 16 + lg * 4 + reg;
        oa[m * 128 + n] = acc[mi][ni][reg];
      }
    }
}

// ---------------- K4: reduce split-K + bias -> out ----------------
__global__ void k_final(const float* __restrict__ outacc,
                        const unsigned short* __restrict__ boc,
                        const int* __restrict__ flag, void* __restrict__ out) {
  int i4 = (blockIdx.x * 256 + threadIdx.x) * 4;
  f32x4 v = *(const f32x4*)&outacc[i4];
  v += *(const f32x4*)&outacc[1048576 + i4];
  v += *(const f32x4*)&outacc[2097152 + i4];
  v += *(const f32x4*)&outacc[3145728 + i4];
  int n0 = i4 & 127;
#pragma unroll
  for (int j = 0; j < 4; ++j) v[j] += bf2f(boc[n0 + j]);
  if (*flag) {
    *(f32x4*)&((float*)out)[i4] = v;
  } else {
    short4v o;
#pragma unroll
    for (int j = 0; j < 4; ++j) o[j] = (short)f2bf(v[j]);
    *(short4v*)&((unsigned short*)out)[i4] = o;
  }
}

extern "C" void kernel_launch(void* const* d_in, const int* in_sizes, int n_in,
                              void* d_out, int out_size, void* d_ws, size_t ws_size,
                              hipStream_t stream) {
  const void* q  = d_in[0];
  const void* k  = d_in[1];
  const void* v  = d_in[2];
  const void* Wq = d_in[3];
  const void* bq = d_in[4];
  const void* Wk = d_in[5];
  const void* bk = d_in[6];
  const void* Wv = d_in[7];
  const void* bv = d_in[8];
  const void* Wo = d_in[9];
  const void* bo = d_in[10];

  char* ws = (char*)d_ws;
  int*            flag = (int*)(ws + 0);
  unsigned short* wqT  = (unsigned short*)(ws + 4096);
  unsigned short* wkT  = (unsigned short*)(ws + 266240);
  unsigned short* wvT  = (unsigned short*)(ws + 528384);
  unsigned short* woT  = (unsigned short*)(ws + 790528);
  unsigned short* bqc  = (unsigned short*)(ws + 1052672);
  unsigned short* bkc  = (unsigned short*)(ws + 1054720);
  unsigned short* bvc  = (unsigned short*)(ws + 1056768);
  unsigned short* boc  = (unsigned short*)(ws + 1058816);
  unsigned short* Xq   = (unsigned short*)(ws + 2097152);   // 2 MB (ml aliases later)
  unsigned short* Xk   = (unsigned short*)(ws + 4194304);   // 2 MB
  unsigned short* Xv   = (unsigned short*)(ws + 6291456);   // 2 MB
  float*          ml   = (float*)(ws + 2097152);            // 1.31 MB, aliases dead Xq
  unsigned short* Qp   = (unsigned short*)(ws + 8388608);   // 16 MB
  unsigned short* Kp   = (unsigned short*)(ws + 25165824);  // 16 MB
  unsigned short* VpT  = (unsigned short*)(ws + 41943040);  // 16 MB
  unsigned short* O    = (unsigned short*)(ws + 58720256);  // 16 MB
  unsigned short* Opart= (unsigned short*)(ws + 75497472);  // 42 MB fp16 partials
  float*          oacc = (float*)(ws + 75497472);           // 16.8 MB (aliases dead Opart)

  const bool use_split = ws_size >= (size_t)117440512;

  k_detect<<<dim3(1), 256, 0, stream>>>((const unsigned short*)q, flag);
  k_cvt<<<dim3(3597), 256, 0, stream>>>(q, k, v, Wq, Wk, Wv, Wo, bq, bk, bv, bo, flag,
                                        Xq, Xk, Xv, wqT, wkT, wvT, woT,
                                        bqc, bkc, bvc, boc);
  k_qkv<<<dim3(128, 8, 3), 256, 0, stream>>>(Xq, Xk, Xv, wqT, wkT, wvT, bqc, bkc, bvc,
                                             Qp, Kp, VpT);
  if (use_split) {
    k_attn_split<<<dim3(1280), 512, 0, stream>>>(Qp, Kp, VpT, Opart, ml, O);
    k_combine<<<dim3(3072), 256, 0, stream>>>(Opart, ml, O);
  } else {
    k_attn<<<dim3(8, 64), 256, 0, stream>>>(Qp, Kp, VpT, O);
  }
  k_oproj<<<dim3(64, 4), 256, 0, stream>>>(O, woT, oacc);
  k_final<<<dim3(1024), 256, 0, stream>>>(oacc, boc, flag, d_out);
}

// Round 20
// 135.325 us; speedup vs baseline: 1.0507x; 1.0507x over previous
//
#include <hip/hip_runtime.h>
#include <hip/hip_bf16.h>

// MultiheadAttention: B=8, T=S=1024, n_heads=8, d_head=128, D=1024.
// FINAL (r15/r18 best-known configuration, 135.5 us):
//   detect dtype -> cvt (x + weights merged) -> QKV proj GEMM (4-wave 64x64
//   wave tiles, B ping-pong, coalesced LDS epilogue) -> split-S flash
//   attention (QBLK=16, 8-wave 512-thread blocks sharing one K/V LDS stream,
//   double-buffered global_load_lds staging, K slot-swizzle + V granule-
//   swizzle, defer-max softmax, ones-MFMA row sums, XCD swizzle, heavy-first
//   dispatch) -> combine -> out-proj split-K (reg ping-pong) -> reduce+bias.

typedef __attribute__((ext_vector_type(8))) short short8;
typedef __attribute__((ext_vector_type(4))) short short4v;
typedef __attribute__((ext_vector_type(4))) float f32x4;

#define B_   8
#define S_   1024
#define DH_  128
#define NH_  8
#define DM_  1024

#define MFMA16(a, b, c) __builtin_amdgcn_mfma_f32_16x16x32_bf16((a), (b), (c), 0, 0, 0)

#define GLOAD_LDS16(gsrc, ldst)                                              \
  __builtin_amdgcn_global_load_lds(                                          \
      (const __attribute__((address_space(1))) void*)(gsrc),                 \
      (__attribute__((address_space(3))) void*)(ldst), 16, 0, 0)

__device__ __forceinline__ float bf2f(unsigned short u) {
  union { unsigned int i; float f; } x; x.i = ((unsigned int)u) << 16; return x.f;
}
__device__ __forceinline__ unsigned short f2bf(float f) {
  union { float f; unsigned int i; } x; x.f = f;
  unsigned int r = (x.i + 0x7fffu + ((x.i >> 16) & 1u)) >> 16;
  return (unsigned short)r;
}
__device__ __forceinline__ unsigned short f2h(float f) {
  union { _Float16 h; unsigned short u; } x; x.h = (_Float16)f; return x.u;
}
__device__ __forceinline__ float h2f(unsigned short u) {
  union { unsigned short u; _Float16 h; } x; x.u = u; return (float)x.h;
}
__device__ __forceinline__ float ldany(const void* p, int i, int fp) {
  return fp ? ((const float*)p)[i] : bf2f(((const unsigned short*)p)[i]);
}

// ---------------- D: input dtype detection ----------------
__global__ void k_detect(const unsigned short* __restrict__ in, int* __restrict__ flag) {
  __shared__ int f;
  int tid = threadIdx.x;
  if (tid == 0) f = 0;
  __syncthreads();
  int t = 0;
  for (int i = tid; i < 16384; i += 256) {
    unsigned h = in[i];
    unsigned e = (h >> 7) & 0xFFu, m = h & 0x7Fu;
    if (e == 0xFFu || (e == 0u && m != 0u)) t = 1;
  }
  if (t) atomicOr(&f, 1);
  __syncthreads();
  if (tid == 0) *flag = f;  // 1 = fp32, 0 = bf16
}

// ---------------- C: merged conversion (q/k/v x8-vec + weights/biases) ----------------
__global__ void k_cvt(const void* __restrict__ q, const void* __restrict__ k,
                      const void* __restrict__ v,
                      const void* __restrict__ Wq, const void* __restrict__ Wk,
                      const void* __restrict__ Wv, const void* __restrict__ Wo,
                      const void* __restrict__ bq, const void* __restrict__ bk,
                      const void* __restrict__ bv, const void* __restrict__ bo,
                      const int* __restrict__ flag,
                      unsigned short* __restrict__ Xq, unsigned short* __restrict__ Xk,
                      unsigned short* __restrict__ Xv,
                      unsigned short* __restrict__ wqT, unsigned short* __restrict__ wkT,
                      unsigned short* __restrict__ wvT, unsigned short* __restrict__ woT,
                      unsigned short* __restrict__ bqc, unsigned short* __restrict__ bkc,
                      unsigned short* __restrict__ bvc, unsigned short* __restrict__ boc) {
  const int fp = *flag;
  if (blockIdx.x < 1536) {
    int z = blockIdx.x / 512, blk = blockIdx.x % 512;
    const void* in = (z == 0) ? q : (z == 1) ? k : v;
    unsigned short* out = (z == 0) ? Xq : (z == 1) ? Xk : Xv;
    int e8 = (blk * 256 + threadIdx.x) * 8;
    if (fp) {
      const float* xf = (const float*)in + e8;
      f32x4 x0 = *(const f32x4*)xf;
      f32x4 x1 = *(const f32x4*)(xf + 4);
      short8 o;
#pragma unroll
      for (int j = 0; j < 4; ++j) { o[j] = (short)f2bf(x0[j]); o[4 + j] = (short)f2bf(x1[j]); }
      *(short8*)&out[e8] = o;
    } else {
      *(short8*)&out[e8] = *(const short8*)((const unsigned short*)in + e8);
    }
    return;
  }
  int g = (blockIdx.x - 1536) * 256 + threadIdx.x;
  if (g < 393216) {
    int z = g >> 17, e = g & 131071;
    const void* in = (z == 0) ? Wq : (z == 1) ? Wk : Wv;
    unsigned short* out = (z == 0) ? wqT : (z == 1) ? wkT : wvT;
    int r = e >> 10, c = e & 1023;
    out[c * 128 + r] = f2bf(ldany(in, e, fp));
  } else if (g < 524288) {
    int e = g - 393216;
    int r = e >> 7, c = e & 127;
    woT[c * 1024 + r] = f2bf(ldany(Wo, e, fp));
  } else if (g < 525312) {
    int e = g - 524288; bqc[e] = f2bf(ldany(bq, e, fp));
  } else if (g < 526336) {
    int e = g - 525312; bkc[e] = f2bf(ldany(bk, e, fp));
  } else if (g < 527360) {
    int e = g - 526336; bvc[e] = f2bf(ldany(bv, e, fp));
  } else if (g < 527488) {
    int e = g - 527360; boc[e] = f2bf(ldany(bo, e, fp));
  }
}

// ---------------- K1: fused QKV projection GEMM ----------------
__global__ __launch_bounds__(256) void k_qkv(
    const unsigned short* __restrict__ Xq, const unsigned short* __restrict__ Xk,
    const unsigned short* __restrict__ Xv,
    const unsigned short* __restrict__ WqT, const unsigned short* __restrict__ WkT,
    const unsigned short* __restrict__ WvT,
    const unsigned short* __restrict__ bq, const unsigned short* __restrict__ bk,
    const unsigned short* __restrict__ bv,
    unsigned short* __restrict__ Qp, unsigned short* __restrict__ Kp,
    unsigned short* __restrict__ VpT) {
  __shared__ __align__(16) unsigned short vtile[128][136];

  const int mat = blockIdx.z;
  const unsigned short* X    = (mat == 0) ? Xq  : (mat == 1) ? Xk  : Xv;
  const unsigned short* WT   = (mat == 0) ? WqT : (mat == 1) ? WkT : WvT;
  const unsigned short* bias = (mat == 0) ? bq  : (mat == 1) ? bk  : bv;
  const float scale = (mat == 0) ? (1.4426950408889634f / 11.313708498984761f) : 1.0f;

  const int tid = threadIdx.x, lane = tid & 63, wave = tid >> 6;
  const int wm = wave >> 1, wn = wave & 1;
  const int l15 = lane & 15, lg = lane >> 4;
  const int mbase = blockIdx.x * 128 + wm * 64;
  const int nbase = blockIdx.y * 128 + wn * 64;

  short8 a[4][4];
#pragma unroll
  for (int mi = 0; mi < 4; ++mi)
#pragma unroll
    for (int kk = 0; kk < 4; ++kk)
      a[mi][kk] = *(const short8*)&X[(mbase + mi * 16 + l15) * DH_ + kk * 32 + lg * 8];

  f32x4 acc[4][4];
#pragma unroll
  for (int mi = 0; mi < 4; ++mi)
#pragma unroll
    for (int ni = 0; ni < 4; ++ni) acc[mi][ni] = (f32x4){0.f, 0.f, 0.f, 0.f};

  short8 bfr[2][4];
#pragma unroll
  for (int kk = 0; kk < 4; ++kk)
    bfr[0][kk] = *(const short8*)&WT[(nbase + l15) * DH_ + kk * 32 + lg * 8];

#pragma unroll
  for (int ni = 0; ni < 4; ++ni) {
    if (ni < 3) {
#pragma unroll
      for (int kk = 0; kk < 4; ++kk)
        bfr[(ni + 1) & 1][kk] =
            *(const short8*)&WT[(nbase + (ni + 1) * 16 + l15) * DH_ + kk * 32 + lg * 8];
    }
#pragma unroll
    for (int mi = 0; mi < 4; ++mi)
#pragma unroll
      for (int kk = 0; kk < 4; ++kk)
        acc[mi][ni] = MFMA16(a[mi][kk], bfr[ni & 1][kk], acc[mi][ni]);
  }

  // stage C tile (bias + scale applied) into vtile
#pragma unroll
  for (int mi = 0; mi < 4; ++mi)
#pragma unroll
    for (int ni = 0; ni < 4; ++ni) {
      int nl = wn * 64 + ni * 16 + l15;
      float bv_ = bf2f(bias[blockIdx.y * 128 + nl]);
#pragma unroll
      for (int reg = 0; reg < 4; ++reg) {
        int ml_ = wm * 64 + mi * 16 + lg * 4 + reg;
        vtile[ml_][nl] = f2bf((acc[mi][ni][reg] + bv_) * scale);
      }
    }
  __syncthreads();

  const int b = blockIdx.x >> 3;
  const int h = blockIdx.y;
  if (mat < 2) {
    unsigned short* Out = ((mat == 0) ? Qp : Kp) +
        ((b * NH_ + h) * S_ + (blockIdx.x & 7) * 128) * DH_;
#pragma unroll
    for (int j = 0; j < 8; ++j) {
      int r = j * 16 + (tid >> 4);
      int c0 = (tid & 15) * 8;
      short8 v = *(const short8*)&vtile[r][c0];
      *(short8*)&Out[j * 2048 + tid * 8] = v;
    }
  } else {
    int n = tid >> 1;
    int thalf = (tid & 1) * 64;
    int base = ((b * NH_ + h) * DH_ + n) * S_ + (blockIdx.x & 7) * 128 + thalf;
#pragma unroll
    for (int jj = 0; jj < 8; ++jj) {
      short8 v;
#pragma unroll
      for (int j2 = 0; j2 < 8; ++j2) v[j2] = (short)vtile[thalf + jj * 8 + j2][n];
      *(short8*)&VpT[base + jj * 8] = v;
    }
  }
}

// ---------------- K2: split-S flash attention, 8-wave blocks, QBLK=16 ----------------
// 1280 blocks x 8 waves (512 thr). Block = (bh, G 0..7 of 8 q-waves, chunk c).
// K/V tiles staged ONCE per block (2 gload/wave), dbuf; K slot-swizzle,
// V granule-swizzle. LDS 44032 -> 3 blocks/CU x 8 waves = 24 waves/CU.
__global__ __launch_bounds__(512) void k_attn_split(
    const unsigned short* __restrict__ Qp, const unsigned short* __restrict__ Kp,
    const unsigned short* __restrict__ VpT,
    unsigned short* __restrict__ Opart, float* __restrict__ ml,
    unsigned short* __restrict__ O) {
  __shared__ __align__(16) unsigned short kbuf[2][4096];  // [32 s][128 d], slot-swizzled
  __shared__ __align__(16) unsigned short vbuf[2][4096];  // [128 d][32 t], granule-swizzled
  __shared__ __align__(16) unsigned short plds[8][16][44];

  const int tid = threadIdx.x, lane = tid & 63, w = tid >> 6;  // w 0..7
  const int l15 = lane & 15, lg = lane >> 4;

  const int bid = blockIdx.x;                      // 1280 = 8 XCD x 160
  const int swz = (bid & 7) * 160 + (bid >> 3);
  const int bh = swz / 20;
  const int bj = swz % 20;                         // heavy (8-tile) blocks first
  int G, c;
  if (bj < 4)        { G = 7; c = bj; }
  else if (bj < 7)   { G = 6; c = bj - 4; }
  else if (bj < 10)  { G = 5; c = bj - 7; }
  else if (bj < 12)  { G = 4; c = bj - 10; }
  else if (bj < 14)  { G = 3; c = bj - 12; }
  else if (bj == 14) { G = 2; c = 0; }
  else if (bj == 15) { G = 1; c = 0; }
  else if (bj == 16) { G = 6; c = 3; }
  else if (bj == 17) { G = 4; c = 2; }
  else if (bj == 18) { G = 2; c = 1; }
  else               { G = 0; c = 0; }
  const int qw = 8 * G + w;                        // 0..63, QBLK=16
  const int q0 = qw * 16;
  const int cd = G >> 1;                           // diagonal chunk (shared by 8 waves)
  const bool dia = (c == cd);
  const int sbeg = c * 256;
  const int nt_w   = dia ? ((qw >> 1) + 1 - 8 * c) : 8;
  const int nt_blk = dia ? (4 * G + 4 - 8 * c) : 8;

  const unsigned short* Qb = Qp + bh * (S_ * DH_);
  const unsigned short* Kb = Kp + bh * (S_ * DH_);
  const unsigned short* Vb = VpT + bh * (DH_ * S_);

  // staging roles: wave w stages K rows [w*4,w*4+4) and V d-rows [w*16,w*16+16)
  const int krow = w * 4 + (lane >> 4);
  const int kslot = lane & 15;
  const int vd   = w * 16 + (lane >> 2);
  const int vslot = lane & 3;
  const int vsw  = vslot ^ ((vd >> 1) & 3);       // inverse-swizzled V source granule

#define STAGE(bb, sb_) do {                                                        \
    GLOAD_LDS16(Kb + ((sb_) + krow) * DH_ + ((kslot ^ (krow & 7)) * 8),            \
                &kbuf[bb][(w * 4) * 128]);                                         \
    GLOAD_LDS16(Vb + vd * S_ + (sb_) + vsw * 8, &vbuf[bb][(w * 16) * 32]);         \
  } while (0)

  short8 qf[4];
#pragma unroll
  for (int kk = 0; kk < 4; ++kk)
    qf[kk] = *(const short8*)&Qb[(q0 + l15) * DH_ + kk * 32 + lg * 8];

  short8 ones;
#pragma unroll
  for (int jj = 0; jj < 8; ++jj) ones[jj] = (short)0x3F80;  // bf16 1.0

  f32x4 of[8], l_acc;
  float m_[4];
#pragma unroll
  for (int di = 0; di < 8; ++di) of[di] = (f32x4){0.f, 0.f, 0.f, 0.f};
  l_acc = (f32x4){0.f, 0.f, 0.f, 0.f};
#pragma unroll
  for (int reg = 0; reg < 4; ++reg) m_[reg] = -1e30f;

  STAGE(0, sbeg);
  __syncthreads();

  const int vrd = lg ^ ((l15 >> 1) & 3);  // swizzled V read granule
  for (int kt = 0; kt < nt_blk; ++kt) {
    const int cb = kt & 1;
    if (kt + 1 < nt_blk) STAGE(cb ^ 1, sbeg + (kt + 1) * 32);  // prefetch under compute

    if (kt < nt_w) {
      const int sb = sbeg + kt * 32;
      const int xsl = l15 & 7;

      f32x4 s0 = (f32x4){0.f, 0.f, 0.f, 0.f}, s1 = (f32x4){0.f, 0.f, 0.f, 0.f};
#pragma unroll
      for (int kk = 0; kk < 4; ++kk) {
        short8 kf0 = *(const short8*)&kbuf[cb][l15 * 128 + (((kk * 4 + lg) ^ xsl) * 8)];
        short8 kf1 = *(const short8*)&kbuf[cb][(16 + l15) * 128 + (((kk * 4 + lg) ^ xsl) * 8)];
        s0 = MFMA16(qf[kk], kf0, s0);
        s1 = MFMA16(qf[kk], kf1, s1);
      }

      if (dia && kt == nt_w - 1) {
        const int qrow = q0 + lg * 4;
#pragma unroll
        for (int reg = 0; reg < 4; ++reg) {
          if (sb + l15 > qrow + reg)      s0[reg] = -1e30f;
          if (sb + 16 + l15 > qrow + reg) s1[reg] = -1e30f;
        }
      }

      // defer-max: rescale only when a row's max grew past m_ + 8
      bool need = false;
      float vmax[4];
#pragma unroll
      for (int reg = 0; reg < 4; ++reg) {
        vmax[reg] = fmaxf(s0[reg], s1[reg]);
        need |= (vmax[reg] > m_[reg] + 8.0f);
      }
      if (__any(need)) {
        float alpha[4];
#pragma unroll
        for (int reg = 0; reg < 4; ++reg) {
          float rm = vmax[reg];
#pragma unroll
          for (int d = 1; d < 16; d <<= 1) rm = fmaxf(rm, __shfl_xor(rm, d));
          float mn = fmaxf(m_[reg], rm);
          alpha[reg] = __builtin_amdgcn_exp2f(m_[reg] - mn);
          m_[reg] = mn;
        }
#pragma unroll
        for (int di = 0; di < 8; ++di)
#pragma unroll
          for (int reg = 0; reg < 4; ++reg) of[di][reg] *= alpha[reg];
#pragma unroll
        for (int reg = 0; reg < 4; ++reg) l_acc[reg] *= alpha[reg];
      }

#pragma unroll
      for (int reg = 0; reg < 4; ++reg) {
        float p0 = __builtin_amdgcn_exp2f(s0[reg] - m_[reg]);
        float p1 = __builtin_amdgcn_exp2f(s1[reg] - m_[reg]);
        union { float f; unsigned int i; } u0, u1;
        u0.f = p0; u1.f = p1;
        plds[w][lg * 4 + reg][l15]      = (unsigned short)((u0.i + 0x8000u) >> 16);
        plds[w][lg * 4 + reg][16 + l15] = (unsigned short)((u1.i + 0x8000u) >> 16);
      }

      short8 pa = *(const short8*)&plds[w][l15][lg * 8];

#pragma unroll
      for (int di = 0; di < 8; ++di) {
        short8 vfd = *(const short8*)&vbuf[cb][(di * 16 + l15) * 32 + vrd * 8];
        of[di] = MFMA16(pa, vfd, of[di]);
      }
      l_acc = MFMA16(pa, ones, l_acc);
    }
    __syncthreads();
  }

  if (qw < 16) {
    // single-chunk causal row: write O directly
    const int b = bh >> 3, h = bh & 7;
#pragma unroll
    for (int reg = 0; reg < 4; ++reg) {
      int row = lg * 4 + reg;
      float inv = 1.0f / l_acc[reg];
      int qq = q0 + row;
#pragma unroll
      for (int di = 0; di < 8; ++di)
        O[(b * S_ + qq) * DM_ + h * DH_ + di * 16 + l15] = f2bf(of[di][reg] * inv);
    }
  } else {
    int runit;
    if (qw < 32)      runit = 16 + 2 * (qw - 16) + c;
    else if (qw < 48) runit = 48 + 3 * (qw - 32) + c;
    else              runit = 96 + 4 * (qw - 48) + c;
    const int g = bh * 160 + runit;
    unsigned short* op = Opart + g * 2048;
    float* mlg = ml + g * 32;
#pragma unroll
    for (int reg = 0; reg < 4; ++reg) {
      int row = lg * 4 + reg;
      float inv = 1.0f / l_acc[reg];
#pragma unroll
      for (int di = 0; di < 8; ++di)
        op[row * 128 + di * 16 + l15] = f2h(of[di][reg] * inv);
      if (l15 == 0) {
        mlg[row * 2]     = m_[reg];
        mlg[row * 2 + 1] = l_acc[reg];
      }
    }
  }
#undef STAGE
}

// ---------------- K2b: combine partials (qw >= 16 only) -> O bf16 ----------------
__global__ void k_combine(const unsigned short* __restrict__ Opart,
                          const float* __restrict__ ml,
                          unsigned short* __restrict__ O) {
  const int bh = blockIdx.x / 48, qw = 16 + blockIdx.x % 48;
  const int nc = (qw >> 4) + 1;  // 2..4
  const int rbase = (qw < 32) ? 16 + 2 * (qw - 16)
                  : (qw < 48) ? 48 + 3 * (qw - 32)
                              : 96 + 4 * (qw - 48);
  const int g0 = bh * 160 + rbase;
  const int tid = threadIdx.x;
  const int row = tid >> 4, d0 = (tid & 15) * 8;

  float m[4], l[4];
  float mx = -1e30f;
  for (int i = 0; i < nc; ++i) {
    m[i] = ml[(g0 + i) * 32 + row * 2];
    l[i] = ml[(g0 + i) * 32 + row * 2 + 1];
    mx = fmaxf(mx, m[i]);
  }
  float wt[4], wsum = 0.f;
  for (int i = 0; i < nc; ++i) { wt[i] = l[i] * exp2f(m[i] - mx); wsum += wt[i]; }
  float invw = 1.0f / wsum;

  float acc[8];
#pragma unroll
  for (int jj = 0; jj < 8; ++jj) acc[jj] = 0.f;
  for (int i = 0; i < nc; ++i) {
    short8 v = *(const short8*)&Opart[(g0 + i) * 2048 + row * 128 + d0];
    float wgt = wt[i];
#pragma unroll
    for (int jj = 0; jj < 8; ++jj) acc[jj] += wgt * h2f((unsigned short)v[jj]);
  }

  const int b = bh >> 3, h = bh & 7;
  const int qq = qw * 16 + row;
  short8 o;
#pragma unroll
  for (int jj = 0; jj < 8; ++jj) o[jj] = (short)f2bf(acc[jj] * invw);
  *(short8*)&O[(b * S_ + qq) * DM_ + h * DH_ + d0] = o;
}

// ---------------- K2-fallback: single-pass causal flash attention ----------------
__global__ __launch_bounds__(256) void k_attn(
    const unsigned short* __restrict__ Qp, const unsigned short* __restrict__ Kp,
    const unsigned short* __restrict__ VpT, unsigned short* __restrict__ O) {
  __shared__ __align__(16) unsigned short plds[4][2][16][44];

  const int qt = 7 - blockIdx.x;
  const int bh = blockIdx.y;
  const int tid = threadIdx.x, lane = tid & 63, w = tid >> 6;
  const int l15 = lane & 15, lg = lane >> 4;
  const int q0 = qt * 128 + w * 32;

  const unsigned short* Qb = Qp + bh * (S_ * DH_);
  const unsigned short* Kb = Kp + bh * (S_ * DH_);
  const unsigned short* Vb = VpT + bh * (DH_ * S_);

  short8 qf[2][4];
#pragma unroll
  for (int mi = 0; mi < 2; ++mi)
#pragma unroll
    for (int kk = 0; kk < 4; ++kk)
      qf[mi][kk] = *(const short8*)&Qb[(q0 + mi * 16 + l15) * DH_ + kk * 32 + lg * 8];

  f32x4 of[2][8];
  float m_[2][4], l_[2][4];
#pragma unroll
  for (int mi = 0; mi < 2; ++mi) {
#pragma unroll
    for (int di = 0; di < 8; ++di) of[mi][di] = (f32x4){0.f, 0.f, 0.f, 0.f};
#pragma unroll
    for (int reg = 0; reg < 4; ++reg) { m_[mi][reg] = -1e30f; l_[mi][reg] = 0.f; }
  }

  const int ntiles = q0 / 32 + 1;
  for (int kt = 0; kt < ntiles; ++kt) {
    const int sb = kt * 32;
    const bool lastt = (kt == ntiles - 1);

    f32x4 s[2][2];
#pragma unroll
    for (int mi = 0; mi < 2; ++mi)
#pragma unroll
      for (int ni = 0; ni < 2; ++ni) s[mi][ni] = (f32x4){0.f, 0.f, 0.f, 0.f};
#pragma unroll
    for (int ni = 0; ni < 2; ++ni) {
      short8 kf[4];
#pragma unroll
      for (int kk = 0; kk < 4; ++kk)
        kf[kk] = *(const short8*)&Kb[(sb + ni * 16 + l15) * DH_ + kk * 32 + lg * 8];
#pragma unroll
      for (int mi = 0; mi < 2; ++mi)
#pragma unroll
        for (int kk = 0; kk < 4; ++kk)
          s[mi][ni] = MFMA16(qf[mi][kk], kf[kk], s[mi][ni]);
    }

#pragma unroll
    for (int mi = 0; mi < 2; ++mi) {
      float alpha[4];
#pragma unroll
      for (int reg = 0; reg < 4; ++reg) {
        int q = q0 + mi * 16 + lg * 4 + reg;
        float v0 = s[mi][0][reg];
        float v1 = s[mi][1][reg];
        if (lastt) {
          if (sb + l15 > q)      v0 = -1e30f;
          if (sb + 16 + l15 > q) v1 = -1e30f;
        }
        float rmax = fmaxf(v0, v1);
#pragma unroll
        for (int d = 1; d < 16; d <<= 1) rmax = fmaxf(rmax, __shfl_xor(rmax, d));
        float mn = fmaxf(m_[mi][reg], rmax);
        alpha[reg] = __builtin_amdgcn_exp2f(m_[mi][reg] - mn);
        m_[mi][reg] = mn;
        float p0 = __builtin_amdgcn_exp2f(v0 - mn), p1 = __builtin_amdgcn_exp2f(v1 - mn);
        float rs = p0 + p1;
#pragma unroll
        for (int d = 1; d < 16; d <<= 1) rs += __shfl_xor(rs, d);
        l_[mi][reg] = l_[mi][reg] * alpha[reg] + rs;
        plds[w][mi][lg * 4 + reg][l15]      = f2bf(p0);
        plds[w][mi][lg * 4 + reg][16 + l15] = f2bf(p1);
      }
#pragma unroll
      for (int di = 0; di < 8; ++di)
#pragma unroll
        for (int reg = 0; reg < 4; ++reg) of[mi][di][reg] *= alpha[reg];
    }

    short8 pa[2];
#pragma unroll
    for (int mi = 0; mi < 2; ++mi)
      pa[mi] = *(const short8*)&plds[w][mi][l15][lg * 8];

#pragma unroll
    for (int di = 0; di < 8; ++di) {
      short8 vf = *(const short8*)&Vb[(di * 16 + l15) * S_ + sb + lg * 8];
#pragma unroll
      for (int mi = 0; mi < 2; ++mi) of[mi][di] = MFMA16(pa[mi], vf, of[mi][di]);
    }
  }

  const int b = bh >> 3, h = bh & 7;
#pragma unroll
  for (int mi = 0; mi < 2; ++mi)
#pragma unroll
    for (int reg = 0; reg < 4; ++reg) {
      float inv = 1.0f / l_[mi][reg];
      int q = q0 + mi * 16 + lg * 4 + reg;
#pragma unroll
      for (int di = 0; di < 8; ++di) {
        int d = di * 16 + l15;
        O[(b * S_ + q) * DM_ + h * DH_ + d] = f2bf(of[mi][di][reg] * inv);
      }
    }
}

// ---------------- K3: out-proj split-K GEMM (reg ping-pong) ----------------
__global__ __launch_bounds__(256) void k_oproj(
    const unsigned short* __restrict__ O, const unsigned short* __restrict__ WoT,
    float* __restrict__ outacc) {
  const int tid = threadIdx.x, lane = tid & 63, wave = tid >> 6;
  const int wm = wave >> 1, wn = wave & 1;
  const int l15 = lane & 15, lg = lane >> 4;
  const int mbase = blockIdx.x * 128 + wm * 64;
  const int kc = blockIdx.y;

  f32x4 acc[4][4];
#pragma unroll
  for (int mi = 0; mi < 4; ++mi)
#pragma unroll
    for (int ni = 0; ni < 4; ++ni) acc[mi][ni] = (f32x4){0.f, 0.f, 0.f, 0.f};

  short8 a[2][4], bfr[2][4];
  {
    int kb = kc * 256;
#pragma unroll
    for (int mi = 0; mi < 4; ++mi)
      a[0][mi] = *(const short8*)&O[(mbase + mi * 16 + l15) * DM_ + kb + lg * 8];
#pragma unroll
    for (int ni = 0; ni < 4; ++ni)
      bfr[0][ni] = *(const short8*)&WoT[(wn * 64 + ni * 16 + l15) * DM_ + kb + lg * 8];
  }

#pragma unroll
  for (int ks = 0; ks < 8; ++ks) {
    const int cur = ks & 1;
    if (ks < 7) {
      int kb = kc * 256 + (ks + 1) * 32;
#pragma unroll
      for (int mi = 0; mi < 4; ++mi)
        a[cur ^ 1][mi] = *(const short8*)&O[(mbase + mi * 16 + l15) * DM_ + kb + lg * 8];
#pragma unroll
      for (int ni = 0; ni < 4; ++ni)
        bfr[cur ^ 1][ni] = *(const short8*)&WoT[(wn * 64 + ni * 16 + l15) * DM_ + kb + lg * 8];
    }
#pragma unroll
    for (int mi = 0; mi < 4; ++mi)
#pragma unroll
      for (int ni = 0; ni < 4; ++ni)
        acc[mi][ni] = MFMA16(a[cur][mi], bfr[cur][ni], acc[mi][ni]);
  }

  float* oa = outacc + kc * (8192 * 128);
#pragma unroll
  for (int mi = 0; mi < 4; ++mi)
#pragma unroll
    for (int ni = 0; ni < 4; ++ni) {
      int n = wn * 64 + ni * 16 + l15;
#pragma unroll
      for (int reg = 0; reg < 4; ++reg) {
        int m = mbase + mi * 16 + lg * 4 + reg;
        oa[m * 128 + n] = acc[mi][ni][reg];
      }
    }
}

// ---------------- K4: reduce split-K + bias -> out ----------------
__global__ void k_final(const float* __restrict__ outacc,
                        const unsigned short* __restrict__ boc,
                        const int* __restrict__ flag, void* __restrict__ out) {
  int i4 = (blockIdx.x * 256 + threadIdx.x) * 4;
  f32x4 v = *(const f32x4*)&outacc[i4];
  v += *(const f32x4*)&outacc[1048576 + i4];
  v += *(const f32x4*)&outacc[2097152 + i4];
  v += *(const f32x4*)&outacc[3145728 + i4];
  int n0 = i4 & 127;
#pragma unroll
  for (int j = 0; j < 4; ++j) v[j] += bf2f(boc[n0 + j]);
  if (*flag) {
    *(f32x4*)&((float*)out)[i4] = v;
  } else {
    short4v o;
#pragma unroll
    for (int j = 0; j < 4; ++j) o[j] = (short)f2bf(v[j]);
    *(short4v*)&((unsigned short*)out)[i4] = o;
  }
}

extern "C" void kernel_launch(void* const* d_in, const int* in_sizes, int n_in,
                              void* d_out, int out_size, void* d_ws, size_t ws_size,
                              hipStream_t stream) {
  const void* q  = d_in[0];
  const void* k  = d_in[1];
  const void* v  = d_in[2];
  const void* Wq = d_in[3];
  const void* bq = d_in[4];
  const void* Wk = d_in[5];
  const void* bk = d_in[6];
  const void* Wv = d_in[7];
  const void* bv = d_in[8];
  const void* Wo = d_in[9];
  const void* bo = d_in[10];

  char* ws = (char*)d_ws;
  int*            flag = (int*)(ws + 0);
  unsigned short* wqT  = (unsigned short*)(ws + 4096);
  unsigned short* wkT  = (unsigned short*)(ws + 266240);
  unsigned short* wvT  = (unsigned short*)(ws + 528384);
  unsigned short* woT  = (unsigned short*)(ws + 790528);
  unsigned short* bqc  = (unsigned short*)(ws + 1052672);
  unsigned short* bkc  = (unsigned short*)(ws + 1054720);
  unsigned short* bvc  = (unsigned short*)(ws + 1056768);
  unsigned short* boc  = (unsigned short*)(ws + 1058816);
  unsigned short* Xq   = (unsigned short*)(ws + 2097152);   // 2 MB (ml aliases later)
  unsigned short* Xk   = (unsigned short*)(ws + 4194304);   // 2 MB
  unsigned short* Xv   = (unsigned short*)(ws + 6291456);   // 2 MB
  float*          ml   = (float*)(ws + 2097152);            // 1.31 MB, aliases dead Xq
  unsigned short* Qp   = (unsigned short*)(ws + 8388608);   // 16 MB
  unsigned short* Kp   = (unsigned short*)(ws + 25165824);  // 16 MB
  unsigned short* VpT  = (unsigned short*)(ws + 41943040);  // 16 MB
  unsigned short* O    = (unsigned short*)(ws + 58720256);  // 16 MB
  unsigned short* Opart= (unsigned short*)(ws + 75497472);  // 42 MB fp16 partials
  float*          oacc = (float*)(ws + 75497472);           // 16.8 MB (aliases dead Opart)

  const bool use_split = ws_size >= (size_t)117440512;

  k_detect<<<dim3(1), 256, 0, stream>>>((const unsigned short*)q, flag);
  k_cvt<<<dim3(3597), 256, 0, stream>>>(q, k, v, Wq, Wk, Wv, Wo, bq, bk, bv, bo, flag,
                                        Xq, Xk, Xv, wqT, wkT, wvT, woT,
                                        bqc, bkc, bvc, boc);
  k_qkv<<<dim3(64, 8, 3), 256, 0, stream>>>(Xq, Xk, Xv, wqT, wkT, wvT, bqc, bkc, bvc,
                                            Qp, Kp, VpT);
  if (use_split) {
    k_attn_split<<<dim3(1280), 512, 0, stream>>>(Qp, Kp, VpT, Opart, ml, O);
    k_combine<<<dim3(3072), 256, 0, stream>>>(Opart, ml, O);
  } else {
    k_attn<<<dim3(8, 64), 256, 0, stream>>>(Qp, Kp, VpT, O);
  }
  k_oproj<<<dim3(64, 4), 256, 0, stream>>>(O, woT, oacc);
  k_final<<<dim3(1024), 256, 0, stream>>>(oacc, boc, flag, d_out);
}